// Round 1
// baseline (262.238 us; speedup 1.0000x reference)
//
#include <hip/hip_runtime.h>
#include <math.h>

#define B_ 2
#define S_ 2048
#define DM 1024
#define NH 16
#define HD 64

typedef unsigned short u16;
typedef __attribute__((ext_vector_type(8))) short bf16x8;
typedef __attribute__((ext_vector_type(4))) float f32x4;

__device__ __forceinline__ u16 f2bf(float x) {
  unsigned u = __float_as_uint(x);
  u = (u + 0x7FFFu + ((u >> 16) & 1u)) >> 16;
  return (u16)u;
}

__device__ __forceinline__ void gload_lds16(const u16* g, u16* l) {
  __builtin_amdgcn_global_load_lds((const __attribute__((address_space(1))) void*)g,
                                   (__attribute__((address_space(3))) void*)l, 16, 0, 0);
}

__global__ void cvt_f32_bf16(const float* __restrict__ in, u16* __restrict__ out, int n4) {
  int i = blockIdx.x * blockDim.x + threadIdx.x;
  int stride = gridDim.x * blockDim.x;
  for (; i < n4; i += stride) {
    float4 v = ((const float4*)in)[i];
    ushort4 o;
    o.x = f2bf(v.x); o.y = f2bf(v.y); o.z = f2bf(v.z); o.w = f2bf(v.w);
    ((ushort4*)out)[i] = o;
  }
}

// C[M,N] = A[M,K] @ Bw[N,K]^T  (both bf16, fp32 accum). 128x128 tile, BK=32,
// 256 threads / 4 waves, each wave 64x64 (4x4 frags of 16x16x32 MFMA).
// MODE 0: scatter bf16 to Q/K/V (B,H,S,64) buffers (N=3072 run).
// MODE 1: f32 + bias to fo (N=1024 run).
template <int MODE>
__global__ __launch_bounds__(256, 2) void gemm_bt(
    const u16* __restrict__ A, const u16* __restrict__ Bw, int K,
    u16* __restrict__ qo, u16* __restrict__ ko, u16* __restrict__ vo,
    float* __restrict__ fo, const float* __restrict__ bias, int N) {
  __shared__ __align__(16) u16 As[128 * 32];
  __shared__ __align__(16) u16 Bs[128 * 32];
  const int tid = threadIdx.x;
  const int wv = tid >> 6, lane = tid & 63;
  const int g = lane >> 4, c = lane & 15;
  const int wr = wv >> 1, wc = wv & 1;
  const int Mb = blockIdx.x * 128, Nb = blockIdx.y * 128;

  f32x4 acc[4][4];
#pragma unroll
  for (int i = 0; i < 4; i++)
#pragma unroll
    for (int j = 0; j < 4; j++) acc[i][j] = f32x4{0.f, 0.f, 0.f, 0.f};

  for (int kb = 0; kb < K; kb += 32) {
#pragma unroll
    for (int it = 0; it < 2; ++it) {
      int id = it * 256 + tid;          // 0..511 -> linear LDS element id*8
      int m = id >> 2, kk = (id & 3) * 8;
      gload_lds16(A + (size_t)(Mb + m) * K + kb + kk, As + (it * 4 + wv) * 512);
      gload_lds16(Bw + (size_t)(Nb + m) * K + kb + kk, Bs + (it * 4 + wv) * 512);
    }
    __syncthreads();
    bf16x8 af[4], bfr[4];
#pragma unroll
    for (int mi = 0; mi < 4; mi++)
      af[mi] = *(const bf16x8*)(As + (wr * 64 + mi * 16 + c) * 32 + g * 8);
#pragma unroll
    for (int ni = 0; ni < 4; ni++)
      bfr[ni] = *(const bf16x8*)(Bs + (wc * 64 + ni * 16 + c) * 32 + g * 8);
#pragma unroll
    for (int mi = 0; mi < 4; mi++)
#pragma unroll
      for (int ni = 0; ni < 4; ni++)
        acc[mi][ni] = __builtin_amdgcn_mfma_f32_16x16x32_bf16(af[mi], bfr[ni], acc[mi][ni], 0, 0, 0);
    __syncthreads();
  }

  if (MODE == 0) {
#pragma unroll
    for (int mi = 0; mi < 4; mi++) {
#pragma unroll
      for (int ni = 0; ni < 4; ni++) {
        int n = Nb + wc * 64 + ni * 16 + c;
        int which = n >> 10, nn = n & 1023;
        int h = nn >> 6, d = nn & 63;
        u16* dst = (which == 0) ? qo : (which == 1) ? ko : vo;
#pragma unroll
        for (int r = 0; r < 4; r++) {
          int row = Mb + wr * 64 + mi * 16 + g * 4 + r;
          int b = row >> 11, s = row & 2047;
          dst[(((size_t)(b * NH + h)) * S_ + s) * HD + d] = f2bf(acc[mi][ni][r]);
        }
      }
    }
  } else {
#pragma unroll
    for (int mi = 0; mi < 4; mi++) {
#pragma unroll
      for (int ni = 0; ni < 4; ni++) {
        int n = Nb + wc * 64 + ni * 16 + c;
        float bv = bias[n];
#pragma unroll
        for (int r = 0; r < 4; r++) {
          int row = Mb + wr * 64 + mi * 16 + g * 4 + r;
          fo[(size_t)row * N + n] = acc[mi][ni][r] + bv;
        }
      }
    }
  }
}

// V (BH, S, 64) -> Vt (BH, 64, S), LDS-tiled 64x64.
__global__ void transpose_v(const u16* __restrict__ v, u16* __restrict__ vt) {
  __shared__ __align__(16) u16 tile[64][72];
  const int bh = blockIdx.y;
  const int s0 = blockIdx.x * 64;
  const int t = threadIdx.x;
#pragma unroll
  for (int i = 0; i < 2; i++) {
    int id = t + i * 256;
    int r = id >> 3, c8 = (id & 7) * 8;
    *(bf16x8*)&tile[r][c8] = *(const bf16x8*)(v + ((size_t)bh * S_ + s0 + r) * HD + c8);
  }
  __syncthreads();
#pragma unroll
  for (int i = 0; i < 2; i++) {
    int id = t + i * 256;
    int dcol = id >> 3, s8 = (id & 7) * 8;
    bf16x8 o;
#pragma unroll
    for (int j = 0; j < 8; j++) o[j] = (short)tile[s8 + j][dcol];
    *(bf16x8*)(vt + ((size_t)bh * HD + dcol) * S_ + s0 + s8) = o;
  }
}

// Flash attention. Grid (S/128, B*H). 4 waves, wave owns 32 q-rows.
// K tile [64][72] (kv,d), Vt tile [64][72] (d,kv), P per-wave [32][72].
__global__ __launch_bounds__(256, 2) void attn_kernel(
    const u16* __restrict__ qb, const u16* __restrict__ kb,
    const u16* __restrict__ vtb, const int* __restrict__ kvm,
    u16* __restrict__ ob) {
  __shared__ __align__(16) u16 Kl[64][72];
  __shared__ __align__(16) u16 Vl[64][72];
  __shared__ __align__(16) u16 Pl[4][32][72];

  const int tid = threadIdx.x;
  const int wv = tid >> 6, lane = tid & 63;
  const int g = lane >> 4, c = lane & 15;
  const int bh = blockIdx.y;
  const int b = bh >> 4, h = bh & 15;
  const int q0 = blockIdx.x * 128;
  const size_t bhbase = (size_t)bh * (S_ * HD);

  bf16x8 qf[2][2];
#pragma unroll
  for (int mi = 0; mi < 2; mi++)
#pragma unroll
    for (int ks = 0; ks < 2; ks++)
      qf[mi][ks] = *(const bf16x8*)(qb + bhbase + (size_t)(q0 + wv * 32 + mi * 16 + c) * HD + ks * 32 + g * 8);

  f32x4 Oa[2][4];
#pragma unroll
  for (int mi = 0; mi < 2; mi++)
#pragma unroll
    for (int di = 0; di < 4; di++) Oa[mi][di] = f32x4{0.f, 0.f, 0.f, 0.f};
  float mrun[2][4], lrun[2][4];
#pragma unroll
  for (int mi = 0; mi < 2; mi++)
#pragma unroll
    for (int r = 0; r < 4; r++) { mrun[mi][r] = -INFINITY; lrun[mi][r] = 0.f; }

  const float scale = 0.03125f;  // 1/sqrt(model_dim=1024)

  for (int kv0 = 0; kv0 < S_; kv0 += 64) {
#pragma unroll
    for (int i = 0; i < 2; i++) {
      int id = tid + i * 256;
      int r = id >> 3, c8 = (id & 7) * 8;
      *(bf16x8*)&Kl[r][c8] = *(const bf16x8*)(kb + bhbase + (size_t)(kv0 + r) * HD + c8);
      *(bf16x8*)&Vl[r][c8] = *(const bf16x8*)(vtb + bhbase + (size_t)r * S_ + kv0 + c8);
    }
    __syncthreads();

    int mk[4];
#pragma unroll
    for (int ni = 0; ni < 4; ni++) mk[ni] = kvm[b * S_ + kv0 + ni * 16 + c];

    f32x4 Sa[2][4];
#pragma unroll
    for (int mi = 0; mi < 2; mi++)
#pragma unroll
      for (int ni = 0; ni < 4; ni++) Sa[mi][ni] = f32x4{0.f, 0.f, 0.f, 0.f};
#pragma unroll
    for (int ks = 0; ks < 2; ks++) {
      bf16x8 kf[4];
#pragma unroll
      for (int ni = 0; ni < 4; ni++)
        kf[ni] = *(const bf16x8*)&Kl[ni * 16 + c][ks * 32 + g * 8];
#pragma unroll
      for (int mi = 0; mi < 2; mi++)
#pragma unroll
        for (int ni = 0; ni < 4; ni++)
          Sa[mi][ni] = __builtin_amdgcn_mfma_f32_16x16x32_bf16(qf[mi][ks], kf[ni], Sa[mi][ni], 0, 0, 0);
    }

#pragma unroll
    for (int mi = 0; mi < 2; mi++) {
#pragma unroll
      for (int ni = 0; ni < 4; ni++)
#pragma unroll
        for (int r = 0; r < 4; r++)
          Sa[mi][ni][r] = mk[ni] ? Sa[mi][ni][r] * scale : -INFINITY;
#pragma unroll
      for (int r = 0; r < 4; r++) {
        float v = fmaxf(fmaxf(Sa[mi][0][r], Sa[mi][1][r]), fmaxf(Sa[mi][2][r], Sa[mi][3][r]));
        v = fmaxf(v, __shfl_xor(v, 1));
        v = fmaxf(v, __shfl_xor(v, 2));
        v = fmaxf(v, __shfl_xor(v, 4));
        v = fmaxf(v, __shfl_xor(v, 8));
        float mold = mrun[mi][r];
        float mnew = fmaxf(mold, v);
        float alpha = (mnew == -INFINITY) ? 1.f : expf(mold - mnew);
        float rs = 0.f;
#pragma unroll
        for (int ni = 0; ni < 4; ni++) {
          float p = (mnew == -INFINITY) ? 0.f : expf(Sa[mi][ni][r] - mnew);
          Sa[mi][ni][r] = p;
          rs += p;
        }
        rs += __shfl_xor(rs, 1);
        rs += __shfl_xor(rs, 2);
        rs += __shfl_xor(rs, 4);
        rs += __shfl_xor(rs, 8);
        lrun[mi][r] = lrun[mi][r] * alpha + rs;
        mrun[mi][r] = mnew;
#pragma unroll
        for (int di = 0; di < 4; di++) Oa[mi][di][r] *= alpha;
      }
#pragma unroll
      for (int ni = 0; ni < 4; ni++)
#pragma unroll
        for (int r = 0; r < 4; r++)
          Pl[wv][mi * 16 + g * 4 + r][ni * 16 + c] = f2bf(Sa[mi][ni][r]);
    }
    asm volatile("s_waitcnt lgkmcnt(0)" ::: "memory");
#pragma unroll
    for (int ks = 0; ks < 2; ks++) {
      bf16x8 pf[2], vf[4];
#pragma unroll
      for (int mi = 0; mi < 2; mi++)
        pf[mi] = *(const bf16x8*)&Pl[wv][mi * 16 + c][ks * 32 + g * 8];
#pragma unroll
      for (int di = 0; di < 4; di++)
        vf[di] = *(const bf16x8*)&Vl[di * 16 + c][ks * 32 + g * 8];
#pragma unroll
      for (int mi = 0; mi < 2; mi++)
#pragma unroll
        for (int di = 0; di < 4; di++)
          Oa[mi][di] = __builtin_amdgcn_mfma_f32_16x16x32_bf16(pf[mi], vf[di], Oa[mi][di], 0, 0, 0);
    }
    __syncthreads();
  }

#pragma unroll
  for (int mi = 0; mi < 2; mi++) {
#pragma unroll
    for (int r = 0; r < 4; r++) {
      float inv = 1.f / lrun[mi][r];
      int srow = q0 + wv * 32 + mi * 16 + g * 4 + r;
      size_t base = ((size_t)(b * S_ + srow)) * DM + (size_t)h * HD;
#pragma unroll
      for (int di = 0; di < 4; di++)
        ob[base + di * 16 + c] = f2bf(Oa[mi][di][r] * inv);
    }
  }
}

extern "C" void kernel_launch(void* const* d_in, const int* in_sizes, int n_in,
                              void* d_out, int out_size, void* d_ws, size_t ws_size,
                              hipStream_t stream) {
  const float* q  = (const float*)d_in[0];
  const int* kvm  = (const int*)d_in[1];
  const float* Wq = (const float*)d_in[2];
  const float* Wk = (const float*)d_in[3];
  const float* Wv = (const float*)d_in[4];
  const float* Wo = (const float*)d_in[5];
  const float* bo = (const float*)d_in[6];
  float* out = (float*)d_out;
  char* ws = (char*)d_ws;

  u16* Xbf   = (u16*)(ws);                       // 8 MB (reused as obuf later)
  u16* Wcat  = (u16*)(ws + (8u << 20));          // 6 MB (Wq|Wk|Wv)
  u16* Wobf  = (u16*)(ws + (14u << 20));         // 2 MB
  u16* qbuf  = (u16*)(ws + (16u << 20));         // 8 MB (B,H,S,64)
  u16* kbuf  = (u16*)(ws + (24u << 20));         // 8 MB
  u16* vbuf  = (u16*)(ws + (32u << 20));         // 8 MB
  u16* vtbuf = (u16*)(ws + (40u << 20));         // 8 MB (B,H,64,S)
  u16* obuf  = Xbf;                              // X dead after QKV GEMM

  cvt_f32_bf16<<<2048, 256, 0, stream>>>(q, Xbf, (B_ * S_ * DM) / 4);
  cvt_f32_bf16<<<512, 256, 0, stream>>>(Wq, Wcat, (DM * DM) / 4);
  cvt_f32_bf16<<<512, 256, 0, stream>>>(Wk, Wcat + DM * DM, (DM * DM) / 4);
  cvt_f32_bf16<<<512, 256, 0, stream>>>(Wv, Wcat + 2 * DM * DM, (DM * DM) / 4);
  cvt_f32_bf16<<<512, 256, 0, stream>>>(Wo, Wobf, (DM * DM) / 4);

  gemm_bt<0><<<dim3(32, 24), 256, 0, stream>>>(Xbf, Wcat, DM, qbuf, kbuf, vbuf,
                                               nullptr, nullptr, 3 * DM);
  transpose_v<<<dim3(32, 32), 256, 0, stream>>>(vbuf, vtbuf);
  attn_kernel<<<dim3(16, 32), 256, 0, stream>>>(qbuf, kbuf, vtbuf, kvm, obuf);
  gemm_bt<1><<<dim3(32, 8), 256, 0, stream>>>(obuf, Wobf, DM, nullptr, nullptr,
                                              nullptr, out, bo, DM);
}

// Round 3
// 153.806 us; speedup vs baseline: 1.7050x; 1.7050x over previous
//
#include <hip/hip_runtime.h>
#include <math.h>

#define B_ 2
#define S_ 2048
#define DM 1024
#define NH 16
#define HD 64

typedef unsigned short u16;
typedef unsigned int u32;
typedef __attribute__((ext_vector_type(8))) short bf16x8;
typedef __attribute__((ext_vector_type(4))) float f32x4;

__device__ __forceinline__ u16 f2bf(float x) {
  unsigned u = __float_as_uint(x);
  u = (u + 0x7FFFu + ((u >> 16) & 1u)) >> 16;
  return (u16)u;
}

__device__ __forceinline__ u32 pkbf(float a, float b) {
  return (u32)f2bf(a) | ((u32)f2bf(b) << 16);
}

__device__ __forceinline__ float exp2a(float x) {
  float r;
  asm("v_exp_f32 %0, %1" : "=v"(r) : "v"(x));
  return r;
}

__device__ __forceinline__ void gload_lds16(const u16* g, u16* l) {
  __builtin_amdgcn_global_load_lds((const __attribute__((address_space(1))) void*)g,
                                   (__attribute__((address_space(3))) void*)l, 16, 0, 0);
}

__global__ void cvt_f32_bf16(const float* __restrict__ in, u16* __restrict__ out, int n4) {
  int i = blockIdx.x * blockDim.x + threadIdx.x;
  int stride = gridDim.x * blockDim.x;
  for (; i < n4; i += stride) {
    float4 v = ((const float4*)in)[i];
    ushort4 o;
    o.x = f2bf(v.x); o.y = f2bf(v.y); o.z = f2bf(v.z); o.w = f2bf(v.w);
    ((ushort4*)out)[i] = o;
  }
}

// C[M,N] = A[M,K] @ Bw[N,K]^T  (both bf16, fp32 accum). 128x128 tile, BK=32.
template <int MODE>
__global__ __launch_bounds__(256, 2) void gemm_bt(
    const u16* __restrict__ A, const u16* __restrict__ Bw, int K,
    u16* __restrict__ qo, u16* __restrict__ ko, u16* __restrict__ vo,
    float* __restrict__ fo, const float* __restrict__ bias, int N) {
  __shared__ __align__(16) u16 As[128 * 32];
  __shared__ __align__(16) u16 Bs[128 * 32];
  const int tid = threadIdx.x;
  const int wv = tid >> 6, lane = tid & 63;
  const int g = lane >> 4, c = lane & 15;
  const int wr = wv >> 1, wc = wv & 1;
  const int Mb = blockIdx.x * 128, Nb = blockIdx.y * 128;

  f32x4 acc[4][4];
#pragma unroll
  for (int i = 0; i < 4; i++)
#pragma unroll
    for (int j = 0; j < 4; j++) acc[i][j] = f32x4{0.f, 0.f, 0.f, 0.f};

  for (int kb = 0; kb < K; kb += 32) {
#pragma unroll
    for (int it = 0; it < 2; ++it) {
      int id = it * 256 + tid;
      int m = id >> 2, kk = (id & 3) * 8;
      gload_lds16(A + (size_t)(Mb + m) * K + kb + kk, As + (it * 4 + wv) * 512);
      gload_lds16(Bw + (size_t)(Nb + m) * K + kb + kk, Bs + (it * 4 + wv) * 512);
    }
    __syncthreads();
    bf16x8 af[4], bfr[4];
#pragma unroll
    for (int mi = 0; mi < 4; mi++)
      af[mi] = *(const bf16x8*)(As + (wr * 64 + mi * 16 + c) * 32 + g * 8);
#pragma unroll
    for (int ni = 0; ni < 4; ni++)
      bfr[ni] = *(const bf16x8*)(Bs + (wc * 64 + ni * 16 + c) * 32 + g * 8);
#pragma unroll
    for (int mi = 0; mi < 4; mi++)
#pragma unroll
      for (int ni = 0; ni < 4; ni++)
        acc[mi][ni] = __builtin_amdgcn_mfma_f32_16x16x32_bf16(af[mi], bfr[ni], acc[mi][ni], 0, 0, 0);
    __syncthreads();
  }

  if (MODE == 0) {
#pragma unroll
    for (int mi = 0; mi < 4; mi++) {
#pragma unroll
      for (int ni = 0; ni < 4; ni++) {
        int n = Nb + wc * 64 + ni * 16 + c;
        int which = n >> 10, nn = n & 1023;
        int h = nn >> 6, d = nn & 63;
        u16* dst = (which == 0) ? qo : (which == 1) ? ko : vo;
#pragma unroll
        for (int r = 0; r < 4; r++) {
          int row = Mb + wr * 64 + mi * 16 + g * 4 + r;
          int b = row >> 11, s = row & 2047;
          dst[(((size_t)(b * NH + h)) * S_ + s) * HD + d] = f2bf(acc[mi][ni][r]);
        }
      }
    }
  } else {
#pragma unroll
    for (int mi = 0; mi < 4; mi++) {
#pragma unroll
      for (int ni = 0; ni < 4; ni++) {
        int n = Nb + wc * 64 + ni * 16 + c;
        float bv = bias[n];
#pragma unroll
        for (int r = 0; r < 4; r++) {
          int row = Mb + wr * 64 + mi * 16 + g * 4 + r;
          fo[(size_t)row * N + n] = acc[mi][ni][r] + bv;
        }
      }
    }
  }
}

// V (BH, S, 64) -> Vt (BH, 64, S), LDS-tiled 64x64.
__global__ void transpose_v(const u16* __restrict__ v, u16* __restrict__ vt) {
  __shared__ __align__(16) u16 tile[64][72];
  const int bh = blockIdx.y;
  const int s0 = blockIdx.x * 64;
  const int t = threadIdx.x;
#pragma unroll
  for (int i = 0; i < 2; i++) {
    int id = t + i * 256;
    int r = id >> 3, c8 = (id & 7) * 8;
    *(bf16x8*)&tile[r][c8] = *(const bf16x8*)(v + ((size_t)bh * S_ + s0 + r) * HD + c8);
  }
  __syncthreads();
#pragma unroll
  for (int i = 0; i < 2; i++) {
    int id = t + i * 256;
    int dcol = id >> 3, s8 = (id & 7) * 8;
    bf16x8 o;
#pragma unroll
    for (int j = 0; j < 8; j++) o[j] = (short)tile[s8 + j][dcol];
    *(bf16x8*)(vt + ((size_t)bh * HD + dcol) * S_ + s0 + s8) = o;
  }
}

// Flash attention, swapped-operand form. Grid (S/128, B*H). 4 waves x 32 q-rows.
// S^T = mfma(K_frag, Q_frag): lane (g,c) reg (ni,r) holds S^T[kv=16ni+4g+r][q=c]
// -> softmax stats are one scalar per lane per 16-q chunk (2 shfl_xor each).
// P fragment: built from the lane's OWN registers under the k-order bijection
//   sigma(ks,g,j) = 32ks + 16(j>>2) + 4g + (j&3)
// applied to BOTH PV operands (legal: mfma contracts over hw-k; any bijection
// applied to A and B identically cancels). V^T frag therefore reads two 8B
// chunks per fragment (kv = 32ks+4g.. and +16) instead of one 16B chunk.
// O^T = mfma(V^T_frag, P_frag): alpha / 1/l rescales are lane-uniform.
__global__ __launch_bounds__(256, 2) void attn_kernel(
    const u16* __restrict__ qb, const u16* __restrict__ kb,
    const u16* __restrict__ vtb, const int* __restrict__ kvm,
    u16* __restrict__ ob) {
  __shared__ __align__(16) u16 Kl[64][72];
  __shared__ __align__(16) u16 Vl[64][72];
  __shared__ __align__(16) float Madd[S_];

  const int tid = threadIdx.x;
  const int wv = tid >> 6, lane = tid & 63;
  const int g = lane >> 4, c = lane & 15;
  const int bh = blockIdx.y;
  const int b = bh >> 4, h = bh & 15;
  const int q0 = blockIdx.x * 128;
  const size_t bhbase = (size_t)bh * (S_ * HD);

  // additive mask in exp2 domain: 0 for valid kv, -1e30 for masked
  for (int i = tid; i < S_; i += 256)
    Madd[i] = kvm[b * S_ + i] ? 0.f : -1e30f;

  // Q fragments (B-operand: Q[q-row][k=d])
  bf16x8 qf[2][2];
#pragma unroll
  for (int mi = 0; mi < 2; mi++)
#pragma unroll
    for (int ks = 0; ks < 2; ks++)
      qf[mi][ks] = *(const bf16x8*)(qb + bhbase + (size_t)(q0 + wv * 32 + mi * 16 + c) * HD + ks * 32 + g * 8);

  f32x4 Oa[4][2];  // [di][mi], O^T layout: row=d(di*16+4g+r), col=q(mi*16+c)
#pragma unroll
  for (int di = 0; di < 4; di++)
#pragma unroll
    for (int mi = 0; mi < 2; mi++) Oa[di][mi] = f32x4{0.f, 0.f, 0.f, 0.f};
  float mrun[2] = {-1e30f, -1e30f};
  float lrun[2] = {0.f, 0.f};

  const float c2 = 0.03125f * 1.44269504088896f;  // (1/sqrt(1024)) * log2(e)

  for (int kv0 = 0; kv0 < S_; kv0 += 64) {
#pragma unroll
    for (int i = 0; i < 2; i++) {
      int id = tid + i * 256;
      int r = id >> 3, c8 = (id & 7) * 8;
      *(bf16x8*)&Kl[r][c8] = *(const bf16x8*)(kb + bhbase + (size_t)(kv0 + r) * HD + c8);
      *(bf16x8*)&Vl[r][c8] = *(const bf16x8*)(vtb + bhbase + (size_t)r * S_ + kv0 + c8);
    }
    __syncthreads();

    // S^T: Sa[ni][mi], row = kv (ni*16 + 4g + r), col = q (mi*16 + c)
    f32x4 Sa[4][2];
#pragma unroll
    for (int ni = 0; ni < 4; ni++)
#pragma unroll
      for (int mi = 0; mi < 2; mi++) Sa[ni][mi] = f32x4{0.f, 0.f, 0.f, 0.f};
#pragma unroll
    for (int ks = 0; ks < 2; ks++) {
      bf16x8 kf[4];
#pragma unroll
      for (int ni = 0; ni < 4; ni++)
        kf[ni] = *(const bf16x8*)&Kl[ni * 16 + c][ks * 32 + g * 8];
#pragma unroll
      for (int ni = 0; ni < 4; ni++)
#pragma unroll
        for (int mi = 0; mi < 2; mi++)
          Sa[ni][mi] = __builtin_amdgcn_mfma_f32_16x16x32_bf16(kf[ni], qf[mi][ks], Sa[ni][mi], 0, 0, 0);
    }

    // scale + additive mask (exp2 domain)
    f32x4 ma[4];
#pragma unroll
    for (int ni = 0; ni < 4; ni++)
      ma[ni] = *(const f32x4*)&Madd[kv0 + ni * 16 + g * 4];
#pragma unroll
    for (int ni = 0; ni < 4; ni++)
#pragma unroll
      for (int mi = 0; mi < 2; mi++)
#pragma unroll
        for (int r = 0; r < 4; r++)
          Sa[ni][mi][r] = Sa[ni][mi][r] * c2 + ma[ni][r];

    bf16x8 Pa[2][2];  // [mi][ks]: word j = P[q=c][kv = 32ks+16(j>>2)+4g+(j&3)]
#pragma unroll
    for (int mi = 0; mi < 2; mi++) {
      // tile max over kv for this lane's q
      float tm = fmaxf(fmaxf(Sa[0][mi][0], Sa[0][mi][1]), fmaxf(Sa[0][mi][2], Sa[0][mi][3]));
#pragma unroll
      for (int ni = 1; ni < 4; ni++)
        tm = fmaxf(tm, fmaxf(fmaxf(Sa[ni][mi][0], Sa[ni][mi][1]), fmaxf(Sa[ni][mi][2], Sa[ni][mi][3])));
      tm = fmaxf(tm, __shfl_xor(tm, 16));
      tm = fmaxf(tm, __shfl_xor(tm, 32));
      float mnew = fmaxf(mrun[mi], tm);
      float alpha = exp2a(mrun[mi] - mnew);
      mrun[mi] = mnew;
      float rs = 0.f;
#pragma unroll
      for (int ni = 0; ni < 4; ni++)
#pragma unroll
        for (int r = 0; r < 4; r++) {
          float p = exp2a(Sa[ni][mi][r] - mnew);
          Sa[ni][mi][r] = p;
          rs += p;
        }
      rs += __shfl_xor(rs, 16);
      rs += __shfl_xor(rs, 32);
      lrun[mi] = lrun[mi] * alpha + rs;
#pragma unroll
      for (int di = 0; di < 4; di++)
#pragma unroll
        for (int r = 0; r < 4; r++) Oa[di][mi][r] *= alpha;

      // P frag from OWN regs (sigma k-order): no cross-lane traffic
#pragma unroll
      for (int ks = 0; ks < 2; ks++) {
        union { u32 u[4]; bf16x8 v; } pw;
        pw.u[0] = pkbf(Sa[2 * ks][mi][0], Sa[2 * ks][mi][1]);
        pw.u[1] = pkbf(Sa[2 * ks][mi][2], Sa[2 * ks][mi][3]);
        pw.u[2] = pkbf(Sa[2 * ks + 1][mi][0], Sa[2 * ks + 1][mi][1]);
        pw.u[3] = pkbf(Sa[2 * ks + 1][mi][2], Sa[2 * ks + 1][mi][3]);
        Pa[mi][ks] = pw.v;
      }
    }

    // O^T += V^T_frag * P_frag, V^T read in the same sigma k-order:
    // elem j = V^T[d = di*16+c][kv0 + 32ks + 16(j>>2) + 4g + (j&3)]
#pragma unroll
    for (int ks = 0; ks < 2; ks++) {
      bf16x8 vf[4];
#pragma unroll
      for (int di = 0; di < 4; di++) {
        const u16* vrow = &Vl[di * 16 + c][0];
        union { ushort4 s[2]; bf16x8 v; } vv;
        vv.s[0] = *(const ushort4*)(vrow + ks * 32 + 4 * g);
        vv.s[1] = *(const ushort4*)(vrow + ks * 32 + 16 + 4 * g);
        vf[di] = vv.v;
      }
#pragma unroll
      for (int di = 0; di < 4; di++)
#pragma unroll
        for (int mi = 0; mi < 2; mi++)
          Oa[di][mi] = __builtin_amdgcn_mfma_f32_16x16x32_bf16(vf[di], Pa[mi][ks], Oa[di][mi], 0, 0, 0);
    }
    __syncthreads();
  }

  // epilogue: lane (g,c) holds O^T[d = di*16+4g+r][q = mi*16+c]; packed 8B stores
#pragma unroll
  for (int mi = 0; mi < 2; mi++) {
    float inv = 1.f / lrun[mi];
    int q = q0 + wv * 32 + mi * 16 + c;
    size_t base = ((size_t)(b * S_ + q)) * DM + (size_t)h * HD;
#pragma unroll
    for (int di = 0; di < 4; di++) {
      ushort4 o;
      u32 lo = pkbf(Oa[di][mi][0] * inv, Oa[di][mi][1] * inv);
      u32 hi = pkbf(Oa[di][mi][2] * inv, Oa[di][mi][3] * inv);
      o.x = (u16)(lo & 0xffff); o.y = (u16)(lo >> 16);
      o.z = (u16)(hi & 0xffff); o.w = (u16)(hi >> 16);
      *(ushort4*)(ob + base + di * 16 + g * 4) = o;
    }
  }
}

extern "C" void kernel_launch(void* const* d_in, const int* in_sizes, int n_in,
                              void* d_out, int out_size, void* d_ws, size_t ws_size,
                              hipStream_t stream) {
  const float* q  = (const float*)d_in[0];
  const int* kvm  = (const int*)d_in[1];
  const float* Wq = (const float*)d_in[2];
  const float* Wk = (const float*)d_in[3];
  const float* Wv = (const float*)d_in[4];
  const float* Wo = (const float*)d_in[5];
  const float* bo = (const float*)d_in[6];
  float* out = (float*)d_out;
  char* ws = (char*)d_ws;

  u16* Xbf   = (u16*)(ws);                       // 8 MB (reused as obuf later)
  u16* Wcat  = (u16*)(ws + (8u << 20));          // 6 MB (Wq|Wk|Wv)
  u16* Wobf  = (u16*)(ws + (14u << 20));         // 2 MB
  u16* qbuf  = (u16*)(ws + (16u << 20));         // 8 MB (B,H,S,64)
  u16* kbuf  = (u16*)(ws + (24u << 20));         // 8 MB
  u16* vbuf  = (u16*)(ws + (32u << 20));         // 8 MB
  u16* vtbuf = (u16*)(ws + (40u << 20));         // 8 MB (B,H,64,S)
  u16* obuf  = Xbf;                              // X dead after QKV GEMM

  cvt_f32_bf16<<<2048, 256, 0, stream>>>(q, Xbf, (B_ * S_ * DM) / 4);
  cvt_f32_bf16<<<512, 256, 0, stream>>>(Wq, Wcat, (DM * DM) / 4);
  cvt_f32_bf16<<<512, 256, 0, stream>>>(Wk, Wcat + DM * DM, (DM * DM) / 4);
  cvt_f32_bf16<<<512, 256, 0, stream>>>(Wv, Wcat + 2 * DM * DM, (DM * DM) / 4);
  cvt_f32_bf16<<<512, 256, 0, stream>>>(Wo, Wobf, (DM * DM) / 4);

  gemm_bt<0><<<dim3(32, 24), 256, 0, stream>>>(Xbf, Wcat, DM, qbuf, kbuf, vbuf,
                                               nullptr, nullptr, 3 * DM);
  transpose_v<<<dim3(32, 32), 256, 0, stream>>>(vbuf, vtbuf);
  attn_kernel<<<dim3(16, 32), 256, 0, stream>>>(qbuf, kbuf, vtbuf, kvm, obuf);
  gemm_bt<1><<<dim3(32, 8), 256, 0, stream>>>(obuf, Wobf, DM, nullptr, nullptr,
                                              nullptr, out, bo, DM);
}

// Round 4
// 135.778 us; speedup vs baseline: 1.9314x; 1.1328x over previous
//
#include <hip/hip_runtime.h>
#include <math.h>

#define B_ 2
#define S_ 2048
#define DM 1024
#define NH 16
#define HD 64

typedef unsigned short u16;
typedef unsigned int u32;
typedef __attribute__((ext_vector_type(8))) short bf16x8;
typedef __attribute__((ext_vector_type(4))) float f32x4;

__device__ __forceinline__ u16 f2bf(float x) {
  unsigned u = __float_as_uint(x);
  u = (u + 0x7FFFu + ((u >> 16) & 1u)) >> 16;
  return (u16)u;
}

// packed f32 pair -> bf16 pair (low = first arg), single VALU op
__device__ __forceinline__ u32 cvtpk(float lo, float hi) {
  u32 r;
  asm("v_cvt_pk_bf16_f32 %0, %1, %2" : "=v"(r) : "v"(lo), "v"(hi));
  return r;
}

__device__ __forceinline__ float exp2a(float x) {
  float r;
  asm("v_exp_f32 %0, %1" : "=v"(r) : "v"(x));
  return r;
}

__device__ __forceinline__ void gload_lds16(const u16* g, u16* l) {
  __builtin_amdgcn_global_load_lds((const __attribute__((address_space(1))) void*)g,
                                   (__attribute__((address_space(3))) void*)l, 16, 0, 0);
}

__global__ void cvt_f32_bf16(const float* __restrict__ in, u16* __restrict__ out, int n4) {
  int i = blockIdx.x * blockDim.x + threadIdx.x;
  int stride = gridDim.x * blockDim.x;
  for (; i < n4; i += stride) {
    float4 v = ((const float4*)in)[i];
    ushort4 o;
    o.x = f2bf(v.x); o.y = f2bf(v.y); o.z = f2bf(v.z); o.w = f2bf(v.w);
    ((ushort4*)out)[i] = o;
  }
}

// C[M,N] = A[M,K] @ Bw[N,K]^T  (both bf16, fp32 accum). 128x128 tile, BK=32.
// MODE 0 (N=3072): scatter Q,K to (B,H,S,64); V written TRANSPOSED to
//   vt[(bh*64+d)*S + (s&~63) + pos(s&63)] with the sigma kv-permutation
//   pos(w) = 32*w5 + 8*((w>>2)&3) + 4*w4 + (w&3)  (bijective in 6 bits),
//   so attn's PV fragment is a single contiguous b128 LDS read.
// MODE 1 (N=1024): f32 + bias to fo.
template <int MODE>
__global__ __launch_bounds__(256, 2) void gemm_bt(
    const u16* __restrict__ A, const u16* __restrict__ Bw, int K,
    u16* __restrict__ qo, u16* __restrict__ ko, u16* __restrict__ vo,
    float* __restrict__ fo, const float* __restrict__ bias, int N) {
  __shared__ __align__(16) u16 As[128 * 32];
  __shared__ __align__(16) u16 Bs[128 * 32];
  const int tid = threadIdx.x;
  const int wv = tid >> 6, lane = tid & 63;
  const int g = lane >> 4, c = lane & 15;
  const int wr = wv >> 1, wc = wv & 1;
  const int Mb = blockIdx.x * 128, Nb = blockIdx.y * 128;

  f32x4 acc[4][4];
#pragma unroll
  for (int i = 0; i < 4; i++)
#pragma unroll
    for (int j = 0; j < 4; j++) acc[i][j] = f32x4{0.f, 0.f, 0.f, 0.f};

  for (int kb = 0; kb < K; kb += 32) {
#pragma unroll
    for (int it = 0; it < 2; ++it) {
      int id = it * 256 + tid;
      int m = id >> 2, kk = (id & 3) * 8;
      gload_lds16(A + (size_t)(Mb + m) * K + kb + kk, As + (it * 4 + wv) * 512);
      gload_lds16(Bw + (size_t)(Nb + m) * K + kb + kk, Bs + (it * 4 + wv) * 512);
    }
    __syncthreads();
    bf16x8 af[4], bfr[4];
#pragma unroll
    for (int mi = 0; mi < 4; mi++)
      af[mi] = *(const bf16x8*)(As + (wr * 64 + mi * 16 + c) * 32 + g * 8);
#pragma unroll
    for (int ni = 0; ni < 4; ni++)
      bfr[ni] = *(const bf16x8*)(Bs + (wc * 64 + ni * 16 + c) * 32 + g * 8);
#pragma unroll
    for (int mi = 0; mi < 4; mi++)
#pragma unroll
      for (int ni = 0; ni < 4; ni++)
        acc[mi][ni] = __builtin_amdgcn_mfma_f32_16x16x32_bf16(af[mi], bfr[ni], acc[mi][ni], 0, 0, 0);
    __syncthreads();
  }

  if (MODE == 0) {
#pragma unroll
    for (int mi = 0; mi < 4; mi++) {
#pragma unroll
      for (int ni = 0; ni < 4; ni++) {
        int n = Nb + wc * 64 + ni * 16 + c;
        int which = n >> 10, nn = n & 1023;
        int h = nn >> 6, d = nn & 63;
        int row0 = Mb + wr * 64 + mi * 16 + g * 4;
        int b0 = row0 >> 11, s0 = row0 & 2047;
        if (which == 2) {
          // sigma-permuted V^T write, packed 8B
          int w6 = s0 & 63;
          int pos = ((w6 >> 5) << 5) | (((w6 >> 2) & 3) << 3) | (((w6 >> 4) & 1) << 2);
          uint2 o;
          o.x = cvtpk(acc[mi][ni][0], acc[mi][ni][1]);
          o.y = cvtpk(acc[mi][ni][2], acc[mi][ni][3]);
          *(uint2*)(vo + ((size_t)((b0 * NH + h) * HD + d)) * S_ + (s0 & ~63) + pos) = o;
        } else {
          u16* dst = (which == 0) ? qo : ko;
#pragma unroll
          for (int r = 0; r < 4; r++)
            dst[(((size_t)(b0 * NH + h)) * S_ + s0 + r) * HD + d] = f2bf(acc[mi][ni][r]);
        }
      }
    }
  } else {
#pragma unroll
    for (int mi = 0; mi < 4; mi++) {
#pragma unroll
      for (int ni = 0; ni < 4; ni++) {
        int n = Nb + wc * 64 + ni * 16 + c;
        float bv = bias[n];
#pragma unroll
        for (int r = 0; r < 4; r++) {
          int row = Mb + wr * 64 + mi * 16 + g * 4 + r;
          fo[(size_t)row * N + n] = acc[mi][ni][r] + bv;
        }
      }
    }
  }
}

// Flash attention, swapped-operand form. Grid (S/128, B*H), 512 thr = 8 waves,
// each wave owns 16 q-rows. S^T = mfma(K_frag, Q_frag): lane (g,c) reg (ni,r)
// holds S^T[kv=16ni+4g+r][q=c] -> softmax stats lane-uniform per q (2 shfl_xor).
// P fragment from the lane's OWN regs under k-order bijection
//   sigma(ks,g,j) = 32ks + 16(j>>2) + 4g + (j&3)
// applied to BOTH PV operands; V^T is stored pre-permuted by the producer so
// its fragment is one b128 read. O^T = mfma(V^T_frag, P_frag).
__global__ __launch_bounds__(512, 4) void attn_kernel(
    const u16* __restrict__ qb, const u16* __restrict__ kb,
    const u16* __restrict__ vtb, const int* __restrict__ kvm,
    u16* __restrict__ ob) {
  __shared__ __align__(16) u16 Kl[64][72];
  __shared__ __align__(16) u16 Vl[64][72];
  __shared__ __align__(16) float Madd[S_];

  const int tid = threadIdx.x;
  const int wv = tid >> 6, lane = tid & 63;
  const int g = lane >> 4, c = lane & 15;
  const int bh = blockIdx.y;
  const int b = bh >> 4, h = bh & 15;
  const int q0 = blockIdx.x * 128;
  const size_t bhbase = (size_t)bh * (S_ * HD);

  // additive mask in exp2 domain: 0 for valid kv, -1e30 for masked
  for (int i = tid; i < S_; i += 512)
    Madd[i] = kvm[b * S_ + i] ? 0.f : -1e30f;

  // Q fragment (B-operand: Q[q=q0+wv*16+c][k=d])
  bf16x8 qf[2];
#pragma unroll
  for (int ks = 0; ks < 2; ks++)
    qf[ks] = *(const bf16x8*)(qb + bhbase + (size_t)(q0 + wv * 16 + c) * HD + ks * 32 + g * 8);

  f32x4 Oa[4];  // [di], O^T: row=d(di*16+4g+r), col=q(c)
#pragma unroll
  for (int di = 0; di < 4; di++) Oa[di] = f32x4{0.f, 0.f, 0.f, 0.f};
  float mrun = -1e30f, lrun = 0.f;

  const float c2 = 0.03125f * 1.44269504088896f;  // (1/sqrt(1024)) * log2(e)

  // staging: 512 threads x one 16B chunk each for K and V
  const int srow = tid >> 3;             // 0..63
  const int scol = (tid & 7) * 8;        // u16 col
  const u16* kg = kb + bhbase + (size_t)srow * HD + scol;
  const u16* vg = vtb + ((size_t)(bh * HD + srow)) * S_ + scol;
  u16* klp = &Kl[srow][scol];
  u16* vlp = &Vl[srow][scol];

  for (int kv0 = 0; kv0 < S_; kv0 += 64) {
    *(bf16x8*)klp = *(const bf16x8*)kg;
    *(bf16x8*)vlp = *(const bf16x8*)vg;
    kg += 64 * HD;
    vg += 64;
    __syncthreads();

    // S^T: Sa[ni], row = kv (ni*16 + 4g + r), col = q (c)
    f32x4 Sa[4];
#pragma unroll
    for (int ni = 0; ni < 4; ni++) Sa[ni] = f32x4{0.f, 0.f, 0.f, 0.f};
    __builtin_amdgcn_s_setprio(1);
#pragma unroll
    for (int ks = 0; ks < 2; ks++) {
      bf16x8 kf[4];
#pragma unroll
      for (int ni = 0; ni < 4; ni++)
        kf[ni] = *(const bf16x8*)&Kl[ni * 16 + c][ks * 32 + g * 8];
#pragma unroll
      for (int ni = 0; ni < 4; ni++)
        Sa[ni] = __builtin_amdgcn_mfma_f32_16x16x32_bf16(kf[ni], qf[ks], Sa[ni], 0, 0, 0);
    }
    __builtin_amdgcn_s_setprio(0);

    // scale + additive mask (exp2 domain)
    f32x4 ma[4];
#pragma unroll
    for (int ni = 0; ni < 4; ni++)
      ma[ni] = *(const f32x4*)&Madd[kv0 + ni * 16 + g * 4];
#pragma unroll
    for (int ni = 0; ni < 4; ni++)
#pragma unroll
      for (int r = 0; r < 4; r++)
        Sa[ni][r] = Sa[ni][r] * c2 + ma[ni][r];

    // online softmax (stats lane-uniform per q)
    float tm = fmaxf(fmaxf(Sa[0][0], Sa[0][1]), fmaxf(Sa[0][2], Sa[0][3]));
#pragma unroll
    for (int ni = 1; ni < 4; ni++)
      tm = fmaxf(tm, fmaxf(fmaxf(Sa[ni][0], Sa[ni][1]), fmaxf(Sa[ni][2], Sa[ni][3])));
    tm = fmaxf(tm, __shfl_xor(tm, 16));
    tm = fmaxf(tm, __shfl_xor(tm, 32));
    float mnew = fmaxf(mrun, tm);
    float alpha = exp2a(mrun - mnew);
    mrun = mnew;
    float rs = 0.f;
#pragma unroll
    for (int ni = 0; ni < 4; ni++)
#pragma unroll
      for (int r = 0; r < 4; r++) {
        float p = exp2a(Sa[ni][r] - mnew);
        Sa[ni][r] = p;
        rs += p;
      }
    rs += __shfl_xor(rs, 16);
    rs += __shfl_xor(rs, 32);
    lrun = lrun * alpha + rs;
#pragma unroll
    for (int di = 0; di < 4; di++)
#pragma unroll
      for (int r = 0; r < 4; r++) Oa[di][r] *= alpha;

    // P frag from OWN regs (sigma k-order), packed with cvt_pk
    bf16x8 Pa[2];
#pragma unroll
    for (int ks = 0; ks < 2; ks++) {
      union { u32 u[4]; bf16x8 v; } pw;
      pw.u[0] = cvtpk(Sa[2 * ks][0], Sa[2 * ks][1]);
      pw.u[1] = cvtpk(Sa[2 * ks][2], Sa[2 * ks][3]);
      pw.u[2] = cvtpk(Sa[2 * ks + 1][0], Sa[2 * ks + 1][1]);
      pw.u[3] = cvtpk(Sa[2 * ks + 1][2], Sa[2 * ks + 1][3]);
      Pa[ks] = pw.v;
    }

    // O^T += V^T_frag * P_frag (V^T pre-permuted: single b128 per frag)
    __builtin_amdgcn_s_setprio(1);
#pragma unroll
    for (int ks = 0; ks < 2; ks++) {
      bf16x8 vf[4];
#pragma unroll
      for (int di = 0; di < 4; di++)
        vf[di] = *(const bf16x8*)&Vl[di * 16 + c][ks * 32 + g * 8];
#pragma unroll
      for (int di = 0; di < 4; di++)
        Oa[di] = __builtin_amdgcn_mfma_f32_16x16x32_bf16(vf[di], Pa[ks], Oa[di], 0, 0, 0);
    }
    __builtin_amdgcn_s_setprio(0);
    __syncthreads();
  }

  // epilogue: lane (g,c) holds O^T[d = di*16+4g+r][q = c]; packed 8B stores
  float inv = 1.f / lrun;
  int q = q0 + wv * 16 + c;
  size_t base = ((size_t)(b * S_ + q)) * DM + (size_t)h * HD;
#pragma unroll
  for (int di = 0; di < 4; di++) {
    uint2 o;
    o.x = cvtpk(Oa[di][0] * inv, Oa[di][1] * inv);
    o.y = cvtpk(Oa[di][2] * inv, Oa[di][3] * inv);
    *(uint2*)(ob + base + di * 16 + g * 4) = o;
  }
}

extern "C" void kernel_launch(void* const* d_in, const int* in_sizes, int n_in,
                              void* d_out, int out_size, void* d_ws, size_t ws_size,
                              hipStream_t stream) {
  const float* q  = (const float*)d_in[0];
  const int* kvm  = (const int*)d_in[1];
  const float* Wq = (const float*)d_in[2];
  const float* Wk = (const float*)d_in[3];
  const float* Wv = (const float*)d_in[4];
  const float* Wo = (const float*)d_in[5];
  const float* bo = (const float*)d_in[6];
  float* out = (float*)d_out;
  char* ws = (char*)d_ws;

  u16* Xbf   = (u16*)(ws);                       // 8 MB (reused as obuf later)
  u16* Wcat  = (u16*)(ws + (8u << 20));          // 6 MB (Wq|Wk|Wv)
  u16* Wobf  = (u16*)(ws + (14u << 20));         // 2 MB
  u16* qbuf  = (u16*)(ws + (16u << 20));         // 8 MB (B,H,S,64)
  u16* kbuf  = (u16*)(ws + (24u << 20));         // 8 MB
  u16* vtbuf = (u16*)(ws + (40u << 20));         // 8 MB (B,H,64,S) sigma-permuted
  u16* obuf  = Xbf;                              // X dead after QKV GEMM

  cvt_f32_bf16<<<2048, 256, 0, stream>>>(q, Xbf, (B_ * S_ * DM) / 4);
  cvt_f32_bf16<<<512, 256, 0, stream>>>(Wq, Wcat, (DM * DM) / 4);
  cvt_f32_bf16<<<512, 256, 0, stream>>>(Wk, Wcat + DM * DM, (DM * DM) / 4);
  cvt_f32_bf16<<<512, 256, 0, stream>>>(Wv, Wcat + 2 * DM * DM, (DM * DM) / 4);
  cvt_f32_bf16<<<512, 256, 0, stream>>>(Wo, Wobf, (DM * DM) / 4);

  gemm_bt<0><<<dim3(32, 24), 256, 0, stream>>>(Xbf, Wcat, DM, qbuf, kbuf, vtbuf,
                                               nullptr, nullptr, 3 * DM);
  attn_kernel<<<dim3(16, 32), 512, 0, stream>>>(qbuf, kbuf, vtbuf, kvm, obuf);
  gemm_bt<1><<<dim3(32, 8), 256, 0, stream>>>(obuf, Wobf, DM, nullptr, nullptr,
                                              nullptr, out, bo, DM);
}